// Round 5
// baseline (225.451 us; speedup 1.0000x reference)
//
#include <hip/hip_runtime.h>

// SimpleGraphSAGE on MI355X — round 5.
// dst = repeat(arange(N),16) -> node i's edges are src[16i..16i+16), deg==16.
//
// History: R1 85us/layer (LDS-bound matmul), R2 122us (1563 waves, latency),
// R3 83us/layer (SGPR-W matmul, fp32 gather), R4 72us/layer (bf16 gather:
// FETCH halved 188->90MB but dur -13% only).
// R4 analysis: gather is bound by vmem-instruction latency slots, not bytes
// (R1/R3/R4 all ~1 load-inst per neighbor row, all ~72-87us). Fix: pack 4
// bf16 rows (128B each = 16 lanes x ushort4) into ONE load instruction via
// lane-group decomposition -> 4x fewer latency slots. Cross-group reduce
// with 2 shfl_xor rounds.

#define NN   100000
#define DEG  16
#define F    64
#define KDIM 128
#define NPB  64       // nodes per block
#define STR  65       // LDS row stride (2-way bank alias = free)
#define JPW  16       // output columns per wave
#define EDG  (NN * DEG)

__device__ __forceinline__ ushort f2bf(float f) {        // RNE
    unsigned u = __float_as_uint(f);
    return (ushort)((u + 0x7fffu + ((u >> 16) & 1u)) >> 16);
}
__device__ __forceinline__ float bf2f(ushort u) {
    return __uint_as_float(((unsigned)u) << 16);
}

__global__ __launch_bounds__(256)
void cvt_f32_bf16(const float* __restrict__ in, ushort* __restrict__ out, int n4)
{
    int i = blockIdx.x * 256 + threadIdx.x;
    if (i < n4) {
        float4 v = ((const float4*)in)[i];
        ushort4 o;
        o.x = f2bf(v.x); o.y = f2bf(v.y); o.z = f2bf(v.z); o.w = f2bf(v.w);
        ((ushort4*)out)[i] = o;
    }
}

// ---------------- bf16-gather layer (4-rows-per-load) ----------------
template<bool RELU, bool EMIT_BF16>
__global__ __launch_bounds__(256, 4)
void sage_layer_bf(const float*  __restrict__ self_f32,  // [NN,F]
                   const ushort* __restrict__ gat_bf16,  // [NN,F] bf16 bits
                   const float*  __restrict__ W,         // [KDIM,F]
                   const float*  __restrict__ bias,      // [F]
                   const int*    __restrict__ src,       // [EDG]
                   float*        __restrict__ out_f32,   // [NN,F]
                   ushort*       __restrict__ out_bf16)  // [NN,F] or null
{
    __shared__ float buf[KDIM][STR];       // 33.3 KB
    __shared__ int   idx_lds[NPB * DEG];   // 4 KB  (37.4 KB -> 4 blocks/CU)

    const int tid   = threadIdx.x;
    const int lane  = tid & 63;
    const int wave  = __builtin_amdgcn_readfirstlane(tid >> 6);
    const int node0 = blockIdx.x * NPB;

    // Stage this block's 1024 edge indices. Thread tid covers its OWN wave's
    // node range -> wave-internal lgkm ordering, no barrier needed.
    {
        const int e0 = node0 * DEG + tid * 4;
        int4 v = make_int4(0, 0, 0, 0);
        if (e0 < EDG) v = *(const int4*)(src + e0);   // EDG % 4 == 0
        *(int4*)&idx_lds[tid * 4] = v;
    }

    // Self rows: lane = feature, wave stages its 16 nodes (coalesced 256B).
    #pragma unroll 4
    for (int m = 0; m < NPB / 4; ++m) {
        const int n    = wave * (NPB / 4) + m;
        const int node = node0 + n;
        float v = 0.f;
        if (node < NN) v = self_f32[node * F + lane];
        buf[lane][n] = v;
    }

    // Neighbor means, 4 rows per load instruction:
    //   lane group g = lane>>4 handles neighbor e+g; sub = lane&15 holds
    //   features 4*sub..4*sub+3 as ushort4 (8B/lane, row = 16 lanes x 8B).
    const int sub = lane & 15;
    const int grp = lane >> 4;
    #pragma unroll 2
    for (int m = 0; m < NPB / 4; ++m) {
        const int n    = wave * (NPB / 4) + m;   // uniform
        const int node = node0 + n;              // uniform
        if (node < NN) {
            float s0 = 0.f, s1 = 0.f, s2 = 0.f, s3 = 0.f;
            #pragma unroll
            for (int e = 0; e < DEG; e += 4) {
                const int idx = idx_lds[n * DEG + e + grp];   // 16-lane bcast
                const ushort4 v =
                    *(const ushort4*)(gat_bf16 + (size_t)idx * F + sub * 4);
                s0 += bf2f(v.x); s1 += bf2f(v.y);
                s2 += bf2f(v.z); s3 += bf2f(v.w);
            }
            // Reduce across the 4 lane groups (butterfly over lane bits 4,5).
            s0 += __shfl_xor(s0, 16, 64); s1 += __shfl_xor(s1, 16, 64);
            s2 += __shfl_xor(s2, 16, 64); s3 += __shfl_xor(s3, 16, 64);
            s0 += __shfl_xor(s0, 32, 64); s1 += __shfl_xor(s1, 32, 64);
            s2 += __shfl_xor(s2, 32, 64); s3 += __shfl_xor(s3, 32, 64);
            if (lane < 16) {   // k-major writes, stride 65 -> conflict-free
                buf[F + 4 * sub + 0][n] = s0 * (1.0f / DEG);
                buf[F + 4 * sub + 1][n] = s1 * (1.0f / DEG);
                buf[F + 4 * sub + 2][n] = s2 * (1.0f / DEG);
                buf[F + 4 * sub + 3][n] = s3 * (1.0f / DEG);
            }
        }
    }
    __syncthreads();

    // Matmul: lane = node, wave owns j in [16w,16w+16). W row wave-uniform
    // -> s_load; buf[k][lane] ds_read_b32 2-way alias = free.
    const int j0 = wave * JPW;
    float acc[JPW];
    #pragma unroll
    for (int j = 0; j < JPW; ++j) acc[j] = bias[j0 + j];

    #pragma unroll 4
    for (int k = 0; k < KDIM; ++k) {
        const float v = buf[k][lane];
        const float* Wr = W + k * F + j0;
        #pragma unroll
        for (int j = 0; j < JPW; ++j)
            acc[j] = fmaf(v, Wr[j], acc[j]);
    }

    const int node = node0 + lane;
    if (node < NN) {
        if (RELU) {
            #pragma unroll
            for (int j = 0; j < JPW; ++j) acc[j] = fmaxf(acc[j], 0.f);
        }
        float4* op = (float4*)(out_f32 + node * F + j0);
        #pragma unroll
        for (int t = 0; t < 4; ++t)
            op[t] = make_float4(acc[4 * t], acc[4 * t + 1],
                                acc[4 * t + 2], acc[4 * t + 3]);
        if (EMIT_BF16) {
            uint4 p0, p1;
            #pragma unroll
            for (int t = 0; t < 8; ++t)
                (t < 4 ? (&p0.x)[t] : (&p1.x)[t - 4]) =
                    (unsigned)f2bf(acc[2 * t]) |
                    ((unsigned)f2bf(acc[2 * t + 1]) << 16);
            uint4* ob = (uint4*)(out_bf16 + node * F + j0);  // 32B aligned
            ob[0] = p0; ob[1] = p1;
        }
    }
}

// ---------------- fallback (round-3, all-fp32) ----------------
template<bool RELU>
__global__ __launch_bounds__(256, 4)
void sage_layer_f32(const float* __restrict__ feat,
                    const float* __restrict__ W,
                    const float* __restrict__ bias,
                    const int*   __restrict__ src,
                    float*       __restrict__ out)
{
    __shared__ float buf[KDIM][STR];
    const int tid   = threadIdx.x;
    const int lane  = tid & 63;
    const int wave  = __builtin_amdgcn_readfirstlane(tid >> 6);
    const int node0 = blockIdx.x * NPB;

    #pragma unroll 2
    for (int m = 0; m < NPB / 4; ++m) {
        const int n    = wave * (NPB / 4) + m;
        const int node = node0 + n;
        if (node < NN) {
            buf[lane][n] = feat[node * F + lane];
            const int* sp = src + node * DEG;
            float s = 0.f;
            #pragma unroll
            for (int e = 0; e < DEG; ++e) s += feat[sp[e] * F + lane];
            buf[F + lane][n] = s * (1.0f / DEG);
        }
    }
    __syncthreads();

    const int j0 = wave * JPW;
    float acc[JPW];
    #pragma unroll
    for (int j = 0; j < JPW; ++j) acc[j] = bias[j0 + j];
    #pragma unroll 4
    for (int k = 0; k < KDIM; ++k) {
        const float v = buf[k][lane];
        const float* Wr = W + k * F + j0;
        #pragma unroll
        for (int j = 0; j < JPW; ++j) acc[j] = fmaf(v, Wr[j], acc[j]);
    }
    const int node = node0 + lane;
    if (node < NN) {
        float4* op = (float4*)(out + node * F + j0);
        #pragma unroll
        for (int t = 0; t < 4; ++t) {
            float4 r = make_float4(acc[4 * t], acc[4 * t + 1],
                                   acc[4 * t + 2], acc[4 * t + 3]);
            if (RELU) {
                r.x = fmaxf(r.x, 0.f); r.y = fmaxf(r.y, 0.f);
                r.z = fmaxf(r.z, 0.f); r.w = fmaxf(r.w, 0.f);
            }
            op[t] = r;
        }
    }
}

extern "C" void kernel_launch(void* const* d_in, const int* in_sizes, int n_in,
                              void* d_out, int out_size, void* d_ws, size_t ws_size,
                              hipStream_t stream) {
    const float* x   = (const float*)d_in[0];
    const float* W1  = (const float*)d_in[1];
    const float* b1  = (const float*)d_in[2];
    const float* W2  = (const float*)d_in[3];
    const float* b2  = (const float*)d_in[4];
    const int*   src = (const int*)d_in[5];

    float* out = (float*)d_out;
    const int blocks = (NN + NPB - 1) / NPB;   // 1563

    const size_t hF32 = (size_t)NN * F * sizeof(float);   // 25.6 MB
    const size_t hBF  = (size_t)NN * F * sizeof(ushort);  // 12.8 MB

    if (ws_size >= hF32 + 2 * hBF) {
        float*  h_f32  = (float*)d_ws;
        ushort* x_bf16 = (ushort*)((char*)d_ws + hF32);
        ushort* h_bf16 = (ushort*)((char*)d_ws + hF32 + hBF);

        const int n4 = NN * F / 4;
        cvt_f32_bf16<<<(n4 + 255) / 256, 256, 0, stream>>>(x, x_bf16, n4);
        sage_layer_bf<true,  true ><<<blocks, 256, 0, stream>>>(
            x, x_bf16, W1, b1, src, h_f32, h_bf16);
        sage_layer_bf<false, false><<<blocks, 256, 0, stream>>>(
            h_f32, h_bf16, W2, b2, src, out, nullptr);
    } else {
        float* h = (float*)d_ws;
        sage_layer_f32<true ><<<blocks, 256, 0, stream>>>(x, W1, b1, src, h);
        sage_layer_f32<false><<<blocks, 256, 0, stream>>>(h, W2, b2, src, out);
    }
}